// Round 1
// baseline (95.443 us; speedup 1.0000x reference)
//
#include <hip/hip_runtime.h>
#include <cstdint>
#include <cstddef>

// PNNLayer collapse:  out[n,:] = dists[n,:] @ P + embeds[n,:] @ W2 + b
//   P = (1/32) * (embeds[anchorset_id] @ W1)   [32 x 64] constant
//   => one GEMM: X [100000 x 96] @ Wcat [96 x 64], Wcat = [P ; W2]
//
// R7: remove the As LDS transpose buffer entirely. The 16x16x32 A-fragment
// (lane l holds A[l&15][(l>>4)*8+j]) is 8 CONTIGUOUS row elements, and X rows
// are contiguous in global memory -> each lane loads its fragment directly
// with two float4 loads (wave covers its 16 rows x contiguous cols =
// coalesced). This deletes: 12 ds_write_b64/thread, 2 barriers/tile, the
// persistent loop + prefetch, and 26KB of LDS. Only the read-only 24KB
// B-fragment stage remains (one barrier per block, ever). Blocks are
// non-persistent: 1563 blocks x 64 nodes.

#define N_NODES 100000
#define DIM     64
#define NTILES  1563     // ceil(100000 / 64)

typedef short bf16x8 __attribute__((ext_vector_type(8)));   // 8 bf16 = 4 VGPRs
typedef float f32x4  __attribute__((ext_vector_type(4)));   // MFMA acc

__device__ __forceinline__ unsigned short f2bf(float f) {
    union { float f; unsigned u; } c; c.f = f;
    return (unsigned short)((c.u + 0x7fffu + ((c.u >> 16) & 1u)) >> 16);  // RNE
}
__device__ __forceinline__ float bf2f(unsigned short h) {
    union { unsigned u; float f; } c; c.u = ((unsigned)h) << 16; return c.f;
}
__device__ __forceinline__ unsigned long long pack4h(float a, float b, float c, float d) {
    unsigned short h0 = f2bf(a), h1 = f2bf(b), h2 = f2bf(c), h3 = f2bf(d);
    return (unsigned long long)h0 | ((unsigned long long)h1 << 16) |
           ((unsigned long long)h2 << 32) | ((unsigned long long)h3 << 48);
}
__device__ __forceinline__ unsigned long long pack4l(float a, float b, float c, float d) {
    unsigned short l0 = f2bf(a - bf2f(f2bf(a))), l1 = f2bf(b - bf2f(f2bf(b)));
    unsigned short l2 = f2bf(c - bf2f(f2bf(c))), l3 = f2bf(d - bf2f(f2bf(d)));
    return (unsigned long long)l0 | ((unsigned long long)l1 << 16) |
           ((unsigned long long)l2 << 32) | ((unsigned long long)l3 << 48);
}
__device__ __forceinline__ bf16x8 mk8h(float4 a, float4 b) {
    union { unsigned long long u[2]; bf16x8 v; } t;
    t.u[0] = pack4h(a.x, a.y, a.z, a.w);
    t.u[1] = pack4h(b.x, b.y, b.z, b.w);
    return t.v;
}
__device__ __forceinline__ bf16x8 mk8l(float4 a, float4 b) {
    union { unsigned long long u[2]; bf16x8 v; } t;
    t.u[0] = pack4l(a.x, a.y, a.z, a.w);
    t.u[1] = pack4l(b.x, b.y, b.z, b.w);
    return t.v;
}

// ---- kernel 1 (fused prep+pack): blocks 0-7 compute P -> fragB(ks=0, 4096
//      entries, 2 per thread); blocks 8-39 pack W2 -> fragB(ks=1,2; 8192
//      entries, 1 per thread).
// fragB flat idx = (((ks*4+nt)*2+pl)*64 + lane)*8 + j ;
// element = Wcat[k = ks*32 + (lane>>4)*8 + j][n = nt*16 + (lane&15)]
__global__ __launch_bounds__(256) void pnn_prep(
    const float* __restrict__ embeds, const float* __restrict__ W,
    const int* __restrict__ aid, unsigned short* __restrict__ fragB)
{
    const int b = blockIdx.x, tid = threadIdx.x;
    if (b < 8) {
        const int t = b * 256 + tid;          // 0..2047 : one P entry each
        const int a = t >> 6, d = t & 63;     // a = k (wave-uniform), d = n
        const float* se = embeds + (size_t)aid[a] * DIM;
        float s = 0.f;
        #pragma unroll
        for (int e = 0; e < DIM; ++e) s += se[e] * W[e * DIM + d];  // W1 rows 0..63
        s *= (1.0f / 32.0f);
        const int j = a & 7, quad = a >> 3;           // k = a (ks = 0)
        const int nt = d >> 4, col = d & 15;
        const int lane = quad * 16 + col;
        const unsigned short hi = f2bf(s);
        fragB[((nt * 2 + 0) * 64 + lane) * 8 + j] = hi;
        fragB[((nt * 2 + 1) * 64 + lane) * 8 + j] = f2bf(s - bf2f(hi));
    } else {
        const int w = (b - 8) * 256 + tid;    // 0..8191 : one W2 entry each
        const int j    = w & 7;
        const int lane = (w >> 3) & 63;
        const int pl   = (w >> 9) & 1;
        const int nt   = (w >> 10) & 3;
        const int ks   = 1 + (w >> 12);       // 1..2
        const int k = ks * 32 + (lane >> 4) * 8 + j;   // 32..95
        const int n = nt * 16 + (lane & 15);
        const float v = W[(k + 32) * DIM + n];         // W2 rows 64..127
        unsigned short h = f2bf(v);
        if (pl) h = f2bf(v - bf2f(h));
        fragB[(((ks * 4 + nt) * 2 + pl) * 64 + lane) * 8 + j] = h;
    }
}

// ---- kernel 2: one 64-node tile per block, 4 waves, no A-LDS, no loop ----
__global__ __launch_bounds__(256) void pnn_main(
    const float* __restrict__ embeds,
    const float* __restrict__ dists,
    const unsigned short* __restrict__ fragB,
    const float* __restrict__ bias,
    float* __restrict__ out)
{
    __shared__ __align__(16) unsigned short sB[12288];   // 24 KB B-frags only

    const int tid  = threadIdx.x;

    // stage B fragments into LDS (coalesced; consumed via ds_read_b128)
    #pragma unroll
    for (int i = 0; i < 6; ++i)
        ((uint4*)sB)[i * 256 + tid] = ((const uint4*)fragB)[i * 256 + tid];
    __syncthreads();     // the ONLY barrier in this kernel

    const int wave = tid >> 6;
    const int lane = tid & 63;
    const int quad = lane >> 4;
    const int col  = lane & 15;

    const int n0    = blockIdx.x * 64;
    const int nodeA = n0 + wave * 16 + col;                 // this lane's A-row
    const int nA    = nodeA < N_NODES ? nodeA : N_NODES - 1; // clamp (rows are
    // independent in D = A@B: garbage in a clamped row only affects that row's
    // output, whose store is guarded below)

    // ---- A fragment loads: per-lane direct, coalesced across the wave ----
    // lane supplies A[row = col][k = ks*32 + quad*8 + j], 8 contiguous floats
    const float4* dp = (const float4*)(dists  + (size_t)nA * 32 + quad * 8);
    const float4  d0 = dp[0], d1 = dp[1];                   // ks = 0
    const float4* ep = (const float4*)(embeds + (size_t)nA * 64 + quad * 8);
    const float4  f0 = ep[0], f1 = ep[1];                   // ks = 1
    const float4* gp = (const float4*)(embeds + (size_t)nA * 64 + 32 + quad * 8);
    const float4  g0 = gp[0], g1 = gp[1];                   // ks = 2

    const bf16x8 Ahi0 = mk8h(d0, d1), Alo0 = mk8l(d0, d1);
    const bf16x8 Ahi1 = mk8h(f0, f1), Alo1 = mk8l(f0, f1);
    const bf16x8 Ahi2 = mk8h(g0, g1), Alo2 = mk8l(g0, g1);

    f32x4 acc[4];
    #pragma unroll
    for (int nt = 0; nt < 4; ++nt) {
        const float bb = bias[nt * 16 + col];
        acc[nt][0] = bb; acc[nt][1] = bb; acc[nt][2] = bb; acc[nt][3] = bb;
    }

    const bf16x8* Bl = (const bf16x8*)sB;
    #pragma unroll
    for (int ks = 0; ks < 3; ++ks) {
        const bf16x8 Ahi = (ks == 0) ? Ahi0 : (ks == 1) ? Ahi1 : Ahi2;
        const bf16x8 Alo = (ks == 0) ? Alo0 : (ks == 1) ? Alo1 : Alo2;
        #pragma unroll
        for (int nt = 0; nt < 4; ++nt) {
            const bf16x8 Bh = Bl[((ks * 4 + nt) * 2 + 0) * 64 + lane];
            const bf16x8 Bo = Bl[((ks * 4 + nt) * 2 + 1) * 64 + lane];
            acc[nt] = __builtin_amdgcn_mfma_f32_16x16x32_bf16(Ahi, Bh, acc[nt], 0, 0, 0);
            acc[nt] = __builtin_amdgcn_mfma_f32_16x16x32_bf16(Ahi, Bo, acc[nt], 0, 0, 0);
            acc[nt] = __builtin_amdgcn_mfma_f32_16x16x32_bf16(Alo, Bh, acc[nt], 0, 0, 0);
        }
    }

    // ---- store: D row = node (quad*4 + r), col = dim (nt*16 + col) ----
    #pragma unroll
    for (int r = 0; r < 4; ++r) {
        const int node = n0 + wave * 16 + quad * 4 + r;
        if (node < N_NODES) {
            float* po = out + (size_t)node * DIM + col;
            #pragma unroll
            for (int nt = 0; nt < 4; ++nt) po[nt * 16] = acc[nt][r];
        }
    }
}

extern "C" void kernel_launch(void* const* d_in, const int* in_sizes, int n_in,
                              void* d_out, int out_size, void* d_ws, size_t ws_size,
                              hipStream_t stream) {
    const float* embeds = (const float*)d_in[0];   // [100000,64] f32
    const float* dists  = (const float*)d_in[1];   // [100000,32] f32
    const float* W      = (const float*)d_in[2];   // [128,64] f32
    const float* bias   = (const float*)d_in[3];   // [64] f32
    const int*   aid    = (const int*)d_in[4];     // [32] int32
    float* out = (float*)d_out;                    // [100000,64] f32

    unsigned short* fragB = (unsigned short*)d_ws; // 12288 bf16 = 24.6 KB

    pnn_prep<<<40, 256, 0, stream>>>(embeds, W, aid, fragB);
    pnn_main<<<NTILES, 256, 0, stream>>>(embeds, dists, fragB, bias, out);
}